// Round 1
// baseline (114.451 us; speedup 1.0000x reference)
//
#include <hip/hip_runtime.h>
#include <cstddef>

#define HDIM 2048
#define NE 64
#define TOPK 4
#define BM 64
#define BKF4 16          // float4 columns per K-chunk (BK = 64 floats)
#define NKT 32           // 2048 / 64
#define NTHREADS 256
#define LDSTRIDE 68      // padded LDS row stride (floats), 16B-aligned, conflict-friendly
#define SSTRIDE 65       // score tile stride (floats)

__global__ __launch_bounds__(NTHREADS) void router_kernel(
    const float* __restrict__ x,
    const float* __restrict__ w,
    const float* __restrict__ scale,
    const float* __restrict__ pes,
    float* __restrict__ probs,
    float* __restrict__ tkw,
    float* __restrict__ tki)
{
    __shared__ float Al[BM][LDSTRIDE];
    __shared__ float Bl[NE][LDSTRIDE];
    __shared__ float RS[BM];

    // Epilogue reuses the GEMM LDS: scores in Al region, exp() values in Bl region.
    float* Sl = &Al[0][0];   // [64][65]
    float* Pl = &Bl[0][0];   // [64][65]

    const int tid = threadIdx.x;
    const int r = tid >> 4;          // 0..15
    const int c = tid & 15;          // 0..15
    const int tok0 = blockIdx.x * BM;

    const float4* x4 = (const float4*)x;   // row stride HDIM/4
    const float4* w4 = (const float4*)w;
    const float4* s4 = (const float4*)scale;

    // 4 independent accumulation chains per output (per float4 lane) for accuracy + ILP
    float acc[4][4][4];
    #pragma unroll
    for (int i = 0; i < 4; i++)
        #pragma unroll
        for (int j = 0; j < 4; j++)
            #pragma unroll
            for (int k = 0; k < 4; k++) acc[i][j][k] = 0.f;
    float ssp[4] = {0.f, 0.f, 0.f, 0.f};

    float4 pa[4], pb[4];
    {   // prefetch K-chunk 0
        float4 sc = s4[c];
        #pragma unroll
        for (int u = 0; u < 4; u++) {
            pa[u] = x4[(size_t)(tok0 + r + 16*u) * (HDIM/4) + c];
            float4 wv = w4[(size_t)(r + 16*u) * (HDIM/4) + c];
            pb[u].x = wv.x * sc.x; pb[u].y = wv.y * sc.y;
            pb[u].z = wv.z * sc.z; pb[u].w = wv.w * sc.w;
        }
    }

    for (int kt = 0; kt < NKT; ++kt) {
        __syncthreads();             // previous tile's readers done
        #pragma unroll
        for (int u = 0; u < 4; u++) {
            *(float4*)&Al[r + 16*u][4*c] = pa[u];
            // sum-of-squares from staging regs (each element squared exactly once per c-lane)
            ssp[u] += pa[u].x*pa[u].x + pa[u].y*pa[u].y + pa[u].z*pa[u].z + pa[u].w*pa[u].w;
            *(float4*)&Bl[r + 16*u][4*c] = pb[u];
        }
        __syncthreads();
        if (kt + 1 < NKT) {          // issue next-tile loads; latency hides under compute
            int kc = (kt + 1) * BKF4 + c;
            float4 sc = s4[kc];
            #pragma unroll
            for (int u = 0; u < 4; u++) {
                pa[u] = x4[(size_t)(tok0 + r + 16*u) * (HDIM/4) + kc];
                float4 wv = w4[(size_t)(r + 16*u) * (HDIM/4) + kc];
                pb[u].x = wv.x * sc.x; pb[u].y = wv.y * sc.y;
                pb[u].z = wv.z * sc.z; pb[u].w = wv.w * sc.w;
            }
        }
        #pragma unroll
        for (int ks = 0; ks < 16; ++ks) {
            float4 av[4], bv[4];
            #pragma unroll
            for (int i = 0; i < 4; i++) av[i] = *(const float4*)&Al[r + 16*i][4*ks];
            #pragma unroll
            for (int j = 0; j < 4; j++) bv[j] = *(const float4*)&Bl[c + 16*j][4*ks];
            #pragma unroll
            for (int i = 0; i < 4; i++)
                #pragma unroll
                for (int j = 0; j < 4; j++) {
                    acc[i][j][0] += av[i].x * bv[j].x;
                    acc[i][j][1] += av[i].y * bv[j].y;
                    acc[i][j][2] += av[i].z * bv[j].z;
                    acc[i][j][3] += av[i].w * bv[j].w;
                }
        }
    }

    // reduce ss over the 16 c-lanes (contiguous lanes r*16 .. r*16+15)
    #pragma unroll
    for (int u = 0; u < 4; u++) {
        #pragma unroll
        for (int d = 1; d < 16; d <<= 1)
            ssp[u] += __shfl_xor(ssp[u], d, 64);
    }
    float fnorm[4];
    #pragma unroll
    for (int i = 0; i < 4; i++)
        fnorm[i] = rsqrtf(ssp[i] * (1.0f / HDIM) + 1e-6f) * 0.022097086912079612f; // H^-0.5

    __syncthreads();                 // done reading Al/Bl as GEMM tiles
    #pragma unroll
    for (int i = 0; i < 4; i++)
        #pragma unroll
        for (int j = 0; j < 4; j++) {
            float s = (acc[i][j][0] + acc[i][j][1]) + (acc[i][j][2] + acc[i][j][3]);
            Sl[(r + 16*i) * SSTRIDE + (c + 16*j)] = s * fnorm[i];
        }
    __syncthreads();

    if (tid < BM) {                  // per-token softmax (lanes own tokens; ~2-way LDS banks)
        const int m = tid;
        float mx = -3.0e38f;
        for (int e = 0; e < NE; e++) mx = fmaxf(mx, Sl[m * SSTRIDE + e]);
        float sum = 0.f;
        for (int e = 0; e < NE; e++) {
            float p = __expf(Sl[m * SSTRIDE + e] - mx);
            Pl[m * SSTRIDE + e] = p;
            sum += p;
        }
        RS[m] = 1.0f / sum;
    }
    __syncthreads();

    // cooperative coalesced probs write
    #pragma unroll
    for (int q = 0; q < 4; q++) {
        int f = tid + NTHREADS * q;      // float4 index 0..1023 of the 64x64 tile
        int m = f >> 4;
        int e0 = (f & 15) * 4;
        float rs = RS[m];
        float4 pv;
        pv.x = Pl[m * SSTRIDE + e0 + 0] * rs;
        pv.y = Pl[m * SSTRIDE + e0 + 1] * rs;
        pv.z = Pl[m * SSTRIDE + e0 + 2] * rs;
        pv.w = Pl[m * SSTRIDE + e0 + 3] * rs;
        *(float4*)&probs[(size_t)(tok0 + m) * NE + e0] = pv;
    }

    if (tid < BM) {                  // destructive top-4 on raw scores (exact ordering, lowest-index ties)
        const int m = tid;
        float wv[TOPK]; int idx[TOPK];
        float wsum = 0.f;
        #pragma unroll
        for (int kk = 0; kk < TOPK; ++kk) {
            float best = -3.0e38f; int bi = 0;
            for (int e = 0; e < NE; e++) {
                float v = Sl[m * SSTRIDE + e];
                if (v > best) { best = v; bi = e; }
            }
            Sl[m * SSTRIDE + bi] = -3.4e38f;
            float p = Pl[m * SSTRIDE + bi];
            wv[kk] = p; idx[kk] = bi; wsum += p;
        }
        float inv = 1.0f / wsum;     // softmax denominator cancels exactly in the renorm
        size_t ob = (size_t)(tok0 + m) * TOPK;
        #pragma unroll
        for (int kk = 0; kk < TOPK; kk++) {
            tkw[ob + kk] = wv[kk] * inv * pes[idx[kk]];
            tki[ob + kk] = (float)idx[kk];   // harness reads the flat buffer as float32
        }
    }
}

extern "C" void kernel_launch(void* const* d_in, const int* in_sizes, int n_in,
                              void* d_out, int out_size, void* d_ws, size_t ws_size,
                              hipStream_t stream) {
    const float* x     = (const float*)d_in[0];
    const float* w     = (const float*)d_in[1];
    const float* scale = (const float*)d_in[2];
    const float* pes   = (const float*)d_in[3];
    const int tokens = in_sizes[0] / HDIM;      // 16384
    float* probs = (float*)d_out;
    float* tkw   = probs + (size_t)tokens * NE;
    float* tki   = tkw + (size_t)tokens * TOPK;
    const int grid = tokens / BM;               // 256
    router_kernel<<<grid, NTHREADS, 0, stream>>>(x, w, scale, pes, probs, tkw, tki);
}